// Round 13
// baseline (174.682 us; speedup 1.0000x reference)
//
#include <hip/hip_runtime.h>

typedef float f32x4 __attribute__((ext_vector_type(4)));
typedef short bf16x8 __attribute__((ext_vector_type(8)));

// ---- workspace layout (bytes) ----
// B1s: [16 kb][528 cols][128 B]  (bf16, chunk-swizzled; cols 512-519 router, 520-527 zero)
// W2s: [1024 cols][640 B]        (bf16, chunk-swizzled; rows 256-263 = b2, 264-319 zero)
// ACT: [32768 rows][640 B]       (bf16, chunk-swizzled; k 256-263 = p, 264-319 zero)
// xbf: [32768 rows][2048 B] bf16 LINEAR (no swizzle) — lives in d_out, consumed before gemm2
#define B1S_KBSZ 67584
#define W2S_OFF  1081344
#define ACT_OFF  1736704
// total ws required: 22,708,224 bytes

__device__ __forceinline__ unsigned short f2bf(float f) {
  unsigned int u = __float_as_uint(f);
  return (unsigned short)((u + 0x7FFFu + ((u >> 16) & 1u)) >> 16);
}
__device__ __forceinline__ unsigned int pack2(float a, float b) {
  return (unsigned int)f2bf(a) | ((unsigned int)f2bf(b) << 16);
}
__device__ __forceinline__ unsigned int cvtpk(float a, float b) {
  unsigned int r;
  asm("v_cvt_pk_bf16_f32 %0, %1, %2" : "=v"(r) : "v"(a), "v"(b));
  return r;
}

// ---------------- prep: pack [W1|Wr|0] -> B1s ; [W2;b2;0] -> W2s ----------------
__global__ __launch_bounds__(256) void prep_all(const float* __restrict__ W1,
                                                const float* __restrict__ Wr,
                                                const float* __restrict__ W2,
                                                const float* __restrict__ b2,
                                                unsigned char* __restrict__ B1s,
                                                unsigned char* __restrict__ W2s) {
  if (blockIdx.x < 264) {
    int t = blockIdx.x * 256 + threadIdx.x;
    int c   = t & 7;
    int col = (t >> 3) % 528;
    int kb  = (t >> 3) / 528;
    int e   = col >> 6;
    int hh  = col & 63;
    float v[8];
    #pragma unroll
    for (int jj = 0; jj < 8; ++jj) {
      int k = kb * 64 + c * 8 + jj;
      float f;
      if (col < 512)      f = W1[(e * 1024 + k) * 64 + hh];   // W1[e][k][hh]
      else if (col < 520) f = Wr[k * 8 + (col - 512)];        // Wr[k][e]
      else                f = 0.0f;
      v[jj] = f;
    }
    *(uint4*)(B1s + kb * B1S_KBSZ + col * 128 + ((c ^ (col & 7)) * 16)) =
        make_uint4(pack2(v[0], v[1]), pack2(v[2], v[3]), pack2(v[4], v[5]), pack2(v[6], v[7]));
  } else {
    int t = (blockIdx.x - 264) * 256 + threadIdx.x;
    int cj  = t % 40;
    int col = t / 40;
    float v[8];
    #pragma unroll
    for (int jj = 0; jj < 8; ++jj) {
      int k = cj * 8 + jj;
      float f;
      if (k < 256)      f = W2[k * 1024 + col];          // W2[e][h][c], k=e*32+h
      else if (k < 264) f = b2[(k - 256) * 1024 + col];  // b2[e][c]
      else              f = 0.0f;
      v[jj] = f;
    }
    int dstc = (cj & ~7) | ((cj & 7) ^ (col & 7));
    *(uint4*)(W2s + col * 640 + dstc * 16) =
        make_uint4(pack2(v[0], v[1]), pack2(v[2], v[3]), pack2(v[4], v[5]), pack2(v[6], v[7]));
  }
}

// ---------------- cvt: x f32 [32768][1024] -> xbf bf16 linear [32768][2048 B] ----------------
// pure streaming: 134 MB read + 67 MB write; 64B read / 32B linear write per thread
__global__ __launch_bounds__(256) void cvt_x(const float* __restrict__ x,
                                             unsigned char* __restrict__ xbf) {
  int t = blockIdx.x * 256 + threadIdx.x;  // 2,097,152 threads (grid 8192)
  int row = t >> 6, c2 = t & 63;
  const float* s = x + (size_t)row * 1024 + c2 * 16;
  f32x4 a = *(const f32x4*)s;
  f32x4 b = *(const f32x4*)(s + 4);
  f32x4 c = *(const f32x4*)(s + 8);
  f32x4 d = *(const f32x4*)(s + 12);
  uint4 u0, u1;
  u0.x = cvtpk(a.x, a.y); u0.y = cvtpk(a.z, a.w);
  u0.z = cvtpk(b.x, b.y); u0.w = cvtpk(b.z, b.w);
  u1.x = cvtpk(c.x, c.y); u1.y = cvtpk(c.z, c.w);
  u1.z = cvtpk(d.x, d.y); u1.w = cvtpk(d.z, d.w);
  unsigned char* dst = xbf + (size_t)row * 2048 + c2 * 32;
  *(uint4*)dst = u0;
  *(uint4*)(dst + 16) = u1;
}

// ---------------- kernel 1: 64 rows x 4 experts/block, zero-LDS, B reg-double-buffered ----------------
// grid 1024 = 512 M-tiles x 2 halves; block 256 = 4 waves; wave = 1 expert (64x64)
// router: wave w accumulates router frag for ks in {4w..4w+3}; partials reduced in LDS
__global__ __launch_bounds__(256, 2) void moe_gemm1(
    const unsigned char* __restrict__ xbf, const float* __restrict__ br,
    const float* __restrict__ b1, const unsigned char* __restrict__ B1s,
    unsigned char* __restrict__ ACT) {
  __shared__ __align__(16) unsigned char smem[30720];
  // hb u16[64][136] @0 (17408) ; logitP f32[4][64][8] @17408 ; logit f32[64][8] @25600 ;
  // pb f32[64][8] @27648

  const int tid  = threadIdx.x;
  const int lane = tid & 63;
  const int w    = tid >> 6;   // wave 0..3
  const int f15  = lane & 15;
  const int fhi  = lane >> 4;
  const int k7   = f15 & 7;

  const int wid  = ((blockIdx.x & 7) << 7) + (blockIdx.x >> 3);  // XCD-chunked, 1024=8*128
  const int mt   = wid >> 1;
  const int half = wid & 1;
  const int m0   = mt << 6;
  const int e    = half * 4 + w;

  f32x4 acc[4][4];   // [mf][nf]
  f32x4 accR[4];     // router partial (this wave's 4 ks)
  #pragma unroll
  for (int a = 0; a < 4; ++a) {
    #pragma unroll
    for (int b = 0; b < 4; ++b) acc[a][b] = f32x4{0.f, 0.f, 0.f, 0.f};
    accR[a] = f32x4{0.f, 0.f, 0.f, 0.f};
  }

  // A: linear xbf rows, per-lane (no swizzle)
  const unsigned char* aB  = xbf + (size_t)(m0 + f15) * 2048;        // + mf*32768 + ks*128
  const int chA0 = fhi << 4;
  const int chA1 = (4 + fhi) << 4;
  // B: chunk-swizzled B1s (swizzle baked by prep)
  const unsigned char* bp  = B1s + (size_t)(e * 64 + f15) * 128;     // + kso + i*2048
  const unsigned char* brt = B1s + (size_t)(512 + f15) * 128;        // + kso
  const int ch0 = ((fhi)     ^ k7) << 4;
  const int ch1 = ((4 + fhi) ^ k7) << 4;

  // ---- B register double-buffer: prime ks=0 ----
  bf16x8 b0c[4], b1c[4];
  #pragma unroll
  for (int i = 0; i < 4; ++i) {
    b0c[i] = *(const bf16x8*)(bp + i * 2048 + ch0);
    b1c[i] = *(const bf16x8*)(bp + i * 2048 + ch1);
  }

  #pragma unroll
  for (int ks = 0; ks < 16; ++ks) {
    const size_t kso = (size_t)ks * B1S_KBSZ;
    const bool doR = ((ks >> 2) == w);

    // prefetch B(ks+1) — fully covered by this iteration's MFMA cluster
    bf16x8 b0n[4], b1n[4];
    if (ks < 15) {
      const size_t ksn = kso + B1S_KBSZ;
      #pragma unroll
      for (int i = 0; i < 4; ++i) {
        b0n[i] = *(const bf16x8*)(bp + ksn + i * 2048 + ch0);
        b1n[i] = *(const bf16x8*)(bp + ksn + i * 2048 + ch1);
      }
    }
    // A(ks): L1-hot (all 4 waves read identical rows)
    bf16x8 a0[4], a1[4];
    #pragma unroll
    for (int mf = 0; mf < 4; ++mf) {
      const unsigned char* s_ = aB + mf * 32768 + ks * 128;
      a0[mf] = *(const bf16x8*)(s_ + chA0);
      a1[mf] = *(const bf16x8*)(s_ + chA1);
    }
    bf16x8 r0, r1;
    if (doR) {
      r0 = *(const bf16x8*)(brt + kso + ch0);
      r1 = *(const bf16x8*)(brt + kso + ch1);
    }

    #pragma unroll
    for (int i = 0; i < 4; ++i) {
      #pragma unroll
      for (int mf = 0; mf < 4; ++mf)
        acc[mf][i] = __builtin_amdgcn_mfma_f32_16x16x32_bf16(a0[mf], b0c[i], acc[mf][i], 0, 0, 0);
      #pragma unroll
      for (int mf = 0; mf < 4; ++mf)
        acc[mf][i] = __builtin_amdgcn_mfma_f32_16x16x32_bf16(a1[mf], b1c[i], acc[mf][i], 0, 0, 0);
    }
    if (doR) {
      #pragma unroll
      for (int mf = 0; mf < 4; ++mf)
        accR[mf] = __builtin_amdgcn_mfma_f32_16x16x32_bf16(a0[mf], r0, accR[mf], 0, 0, 0);
      #pragma unroll
      for (int mf = 0; mf < 4; ++mf)
        accR[mf] = __builtin_amdgcn_mfma_f32_16x16x32_bf16(a1[mf], r1, accR[mf], 0, 0, 0);
    }
    // rotate prefetch buffers (register renaming under full unroll)
    if (ks < 15) {
      #pragma unroll
      for (int i = 0; i < 4; ++i) { b0c[i] = b0n[i]; b1c[i] = b1n[i]; }
    }
    if ((ks & 3) == 3) __syncthreads();  // keep waves converged for L1 A-sharing
  }

  unsigned short* hb = (unsigned short*)smem;      // [64][136]: cols 0-127 act, 128-135 p(bf16)
  float* logitP = (float*)(smem + 17408);          // [4][64][8]
  float* logit  = (float*)(smem + 25600);          // [64][8]
  float* pb     = (float*)(smem + 27648);          // [64][8]

  if (f15 < 8) {  // router partials
    #pragma unroll
    for (int mf = 0; mf < 4; ++mf)
      #pragma unroll
      for (int r = 0; r < 4; ++r)
        logitP[(w * 64 + mf * 16 + fhi * 4 + r) * 8 + f15] = accR[mf][r];
  }
  __syncthreads();
  {  // reduce partials + br
    int row = tid >> 2, ep = tid & 3;
    #pragma unroll
    for (int j = 0; j < 2; ++j) {
      int ee = ep * 2 + j;
      float s = logitP[row * 8 + ee] + logitP[(64 + row) * 8 + ee] +
                logitP[(128 + row) * 8 + ee] + logitP[(192 + row) * 8 + ee];
      logit[row * 8 + ee] = s + br[ee];
    }
  }
  __syncthreads();
  if (tid < 64) {  // per-row softmax
    int row = tid;
    const float* lg = logit + row * 8;
    float l0 = lg[0], l1 = lg[1], l2 = lg[2], l3 = lg[3];
    float l4 = lg[4], l5 = lg[5], l6 = lg[6], l7 = lg[7];
    float mx = fmaxf(fmaxf(fmaxf(l0, l1), fmaxf(l2, l3)),
                     fmaxf(fmaxf(l4, l5), fmaxf(l6, l7)));
    float e0 = __expf(l0 - mx), e1 = __expf(l1 - mx), e2 = __expf(l2 - mx), e3 = __expf(l3 - mx);
    float e4 = __expf(l4 - mx), e5 = __expf(l5 - mx), e6 = __expf(l6 - mx), e7 = __expf(l7 - mx);
    float rinv = 1.f / (e0 + e1 + e2 + e3 + e4 + e5 + e6 + e7);
    float p_[8] = {e0 * rinv, e1 * rinv, e2 * rinv, e3 * rinv,
                   e4 * rinv, e5 * rinv, e6 * rinv, e7 * rinv};
    #pragma unroll
    for (int j = 0; j < 8; ++j) {
      pb[row * 8 + j] = p_[j];
      hb[row * 136 + 128 + j] = f2bf(p_[j]);
    }
  }
  __syncthreads();
  {  // SwiGLU scale + stage to hb
    const float b1x0 = b1[e * 64 + f15],      b1x1 = b1[e * 64 + 16 + f15];
    const float b1g0 = b1[e * 64 + 32 + f15], b1g1 = b1[e * 64 + 48 + f15];
    #pragma unroll
    for (int mf = 0; mf < 4; ++mf) {
      #pragma unroll
      for (int r = 0; r < 4; ++r) {
        int row = mf * 16 + fhi * 4 + r;
        float pe = pb[row * 8 + e];
        #pragma unroll
        for (int ci = 0; ci < 2; ++ci) {
          float xv = acc[mf][ci][r]     + (ci ? b1x1 : b1x0);
          float gv = acc[mf][ci + 2][r] + (ci ? b1g1 : b1g0);
          float av = pe * xv * gv / (1.f + __expf(-gv));  // pe * xp * silu(gate)
          hb[row * 136 + w * 32 + ci * 16 + f15] = f2bf(av);
        }
      }
    }
  }
  __syncthreads();
  {  // ACT write: this half's 16 act chunks (+ p/zero chunks from half 0)
    const int row = tid >> 2, q = tid & 3, key = row & 7;
    unsigned char* arow = ACT + (size_t)(m0 + row) * 640;
    const unsigned char* hrow = (const unsigned char*)(hb + row * 136);
    #pragma unroll
    for (int j = 0; j < 4; ++j) {
      int c = q + j * 4;            // 0..15
      int g = half * 16 + c;
      uint4 v = *(const uint4*)(hrow + c * 16);
      *(uint4*)(arow + (g >> 3) * 128 + (((g & 7) ^ key) << 4)) = v;
    }
    if (half == 0) {
      #pragma unroll
      for (int j = 0; j < 2; ++j) {
        int c = q + j * 4;          // 0..7 -> chunks 32..39
        int g = 32 + c;
        uint4 v = make_uint4(0, 0, 0, 0);
        if (c == 0) v = *(const uint4*)(hrow + 256);   // p (bf16 cols 128-135)
        *(uint4*)(arow + (g >> 3) * 128 + (((g & 7) ^ key) << 4)) = v;
      }
    }
  }
}

// ---------------- kernel 2: ACT @ W2s -> out ; zero-LDS, barrier-free K-loop ----------------
// grid 2048 = 256 m x 8 n; block 256 = 4 waves (2 mg x 2 ng), wave 64x64
__global__ __launch_bounds__(256, 3) void moe_gemm2(
    const unsigned char* __restrict__ ACT, const unsigned char* __restrict__ W2s,
    float* __restrict__ out) {
  __shared__ __align__(16) unsigned char smem[32768];  // epilogue slab f32[64][128]
  const int tid  = threadIdx.x;
  const int lane = tid & 63;
  const int w    = tid >> 6;
  const int mg   = w >> 1, ng = w & 1;
  const int f15  = lane & 15, fhi = lane >> 4;
  const int k7   = f15 & 7;

  const int wid = ((blockIdx.x & 7) << 8) + (blockIdx.x >> 3);  // 2048 = 8*256
  const int m0  = (wid >> 3) * 128;
  const int n0  = (wid & 7) * 128;

  f32x4 acc[4][4];
  #pragma unroll
  for (int a = 0; a < 4; ++a)
    #pragma unroll
    for (int b = 0; b < 4; ++b) acc[a][b] = f32x4{0.f, 0.f, 0.f, 0.f};

  const unsigned char* aB = ACT + (size_t)(m0 + mg * 64 + f15) * 640;
  const unsigned char* bB = W2s + (size_t)(n0 + ng * 64 + f15) * 640;
  const int ch0 = ((fhi)     ^ k7) << 4;
  const int ch1 = ((4 + fhi) ^ k7) << 4;

  #pragma unroll
  for (int kb = 0; kb < 5; ++kb) {
    bf16x8 a0[4], a1[4];
    #pragma unroll
    for (int mf = 0; mf < 4; ++mf) {
      const unsigned char* s_ = aB + mf * 10240 + kb * 128;
      a0[mf] = *(const bf16x8*)(s_ + ch0);
      a1[mf] = *(const bf16x8*)(s_ + ch1);
    }
    #pragma unroll
    for (int nf = 0; nf < 4; ++nf) {
      const unsigned char* s_ = bB + nf * 10240 + kb * 128;
      bf16x8 b0 = *(const bf16x8*)(s_ + ch0);
      bf16x8 b1v = *(const bf16x8*)(s_ + ch1);
      #pragma unroll
      for (int mf = 0; mf < 4; ++mf)
        acc[mf][nf] = __builtin_amdgcn_mfma_f32_16x16x32_bf16(a0[mf], b0, acc[mf][nf], 0, 0, 0);
      #pragma unroll
      for (int mf = 0; mf < 4; ++mf)
        acc[mf][nf] = __builtin_amdgcn_mfma_f32_16x16x32_bf16(a1[mf], b1v, acc[mf][nf], 0, 0, 0);
    }
  }

  // epilogue: two 64-row rounds through a swizzled f32 slab -> 512B coalesced stores
  float* slab = (float*)smem;
  #pragma unroll 1
  for (int q = 0; q < 2; ++q) {
    if (mg == q) {
      #pragma unroll
      for (int mf = 0; mf < 4; ++mf)
        #pragma unroll
        for (int nf = 0; nf < 4; ++nf)
          #pragma unroll
          for (int r = 0; r < 4; ++r) {
            int rl  = mf * 16 + fhi * 4 + r;
            int col = ng * 64 + nf * 16 + f15;
            slab[rl * 128 + (col ^ (((rl >> 2) & 7) << 2))] = acc[mf][nf][r];
          }
    }
    __syncthreads();
    #pragma unroll
    for (int j = 0; j < 8; ++j) {
      int rl = (tid >> 5) + j * 8;
      int c4 = tid & 31;
      f32x4 v = *(const f32x4*)(smem + rl * 512 + ((c4 ^ ((rl >> 2) & 7)) << 4));
      *(f32x4*)(out + (size_t)(m0 + q * 64 + rl) * 1024 + n0 + c4 * 4) = v;
    }
    __syncthreads();
  }
}

extern "C" void kernel_launch(void* const* d_in, const int* in_sizes, int n_in,
                              void* d_out, int out_size, void* d_ws, size_t ws_size,
                              hipStream_t stream) {
  const float* x  = (const float*)d_in[0];
  const float* Wr = (const float*)d_in[1];
  const float* br = (const float*)d_in[2];
  const float* W1 = (const float*)d_in[3];
  const float* b1 = (const float*)d_in[4];
  const float* W2 = (const float*)d_in[5];
  const float* b2 = (const float*)d_in[6];
  float* out = (float*)d_out;
  unsigned char* ws  = (unsigned char*)d_ws;
  unsigned char* B1s = ws;
  unsigned char* W2s = ws + W2S_OFF;
  unsigned char* ACT = ws + ACT_OFF;
  unsigned char* xbf = (unsigned char*)d_out;  // 67 MB scratch inside the 134 MB output buffer;
                                               // consumed by gemm1 before gemm2 overwrites d_out

  hipLaunchKernelGGL(prep_all, dim3(424), dim3(256), 0, stream, W1, Wr, W2, b2, B1s, W2s);
  hipLaunchKernelGGL(cvt_x, dim3(8192), dim3(256), 0, stream, x, xbf);
  hipLaunchKernelGGL(moe_gemm1, dim3(1024), dim3(256), 0, stream, xbf, br, b1, B1s, ACT);
  hipLaunchKernelGGL(moe_gemm2, dim3(2048), dim3(256), 0, stream, ACT, W2s, out);
}

// Round 14
// 135.049 us; speedup vs baseline: 1.2935x; 1.2935x over previous
//
#include <hip/hip_runtime.h>

typedef float f32x4 __attribute__((ext_vector_type(4)));
typedef short bf16x8 __attribute__((ext_vector_type(8)));

// ---- workspace layout (bytes) ----
// B1s: [16 kb][528 cols][128 B]  (bf16, chunk-swizzled; cols 512-519 router, 520-527 zero)
// W2s: [1024 cols][640 B]        (bf16, chunk-swizzled; rows 256-263 = b2, 264-319 zero)
// ACT: [32768 rows][640 B]       (bf16, chunk-swizzled; k 256-263 = p, 264-319 zero)
#define B1S_KBSZ 67584
#define W2S_OFF  1081344
#define ACT_OFF  1736704
// total ws required: 22,708,224 bytes

__device__ __forceinline__ unsigned short f2bf(float f) {
  unsigned int u = __float_as_uint(f);
  return (unsigned short)((u + 0x7FFFu + ((u >> 16) & 1u)) >> 16);
}
__device__ __forceinline__ unsigned int pack2(float a, float b) {
  return (unsigned int)f2bf(a) | ((unsigned int)f2bf(b) << 16);
}
__device__ __forceinline__ unsigned int cvtpk(float a, float b) {
  unsigned int r;
  asm("v_cvt_pk_bf16_f32 %0, %1, %2" : "=v"(r) : "v"(a), "v"(b));
  return r;
}
__device__ __forceinline__ void async16(const void* g, void* l) {
  __builtin_amdgcn_global_load_lds(
      (const __attribute__((address_space(1))) unsigned int*)g,
      (__attribute__((address_space(3))) unsigned int*)l, 16, 0, 0);
}

// ---------------- prep: pack [W1|Wr|0] -> B1s ; [W2;b2;0] -> W2s ----------------
__global__ __launch_bounds__(256) void prep_all(const float* __restrict__ W1,
                                                const float* __restrict__ Wr,
                                                const float* __restrict__ W2,
                                                const float* __restrict__ b2,
                                                unsigned char* __restrict__ B1s,
                                                unsigned char* __restrict__ W2s) {
  if (blockIdx.x < 264) {
    int t = blockIdx.x * 256 + threadIdx.x;
    int c   = t & 7;
    int col = (t >> 3) % 528;
    int kb  = (t >> 3) / 528;
    int e   = col >> 6;
    int hh  = col & 63;
    float v[8];
    #pragma unroll
    for (int jj = 0; jj < 8; ++jj) {
      int k = kb * 64 + c * 8 + jj;
      float f;
      if (col < 512)      f = W1[(e * 1024 + k) * 64 + hh];   // W1[e][k][hh]
      else if (col < 520) f = Wr[k * 8 + (col - 512)];        // Wr[k][e]
      else                f = 0.0f;
      v[jj] = f;
    }
    *(uint4*)(B1s + kb * B1S_KBSZ + col * 128 + ((c ^ (col & 7)) * 16)) =
        make_uint4(pack2(v[0], v[1]), pack2(v[2], v[3]), pack2(v[4], v[5]), pack2(v[6], v[7]));
  } else {
    int t = (blockIdx.x - 264) * 256 + threadIdx.x;
    int cj  = t % 40;
    int col = t / 40;
    float v[8];
    #pragma unroll
    for (int jj = 0; jj < 8; ++jj) {
      int k = cj * 8 + jj;
      float f;
      if (k < 256)      f = W2[k * 1024 + col];          // W2[e][h][c], k=e*32+h
      else if (k < 264) f = b2[(k - 256) * 1024 + col];  // b2[e][c]
      else              f = 0.0f;
      v[jj] = f;
    }
    int dstc = (cj & ~7) | ((cj & 7) ^ (col & 7));
    *(uint4*)(W2s + col * 640 + dstc * 16) =
        make_uint4(pack2(v[0], v[1]), pack2(v[2], v[3]), pack2(v[4], v[5]), pack2(v[6], v[7]));
  }
}

// ---------------- kernel 1: per expert-pair tile, fused router/softmax/SwiGLU (R1, 103 us) ----------------
// grid 1024 = 256 M-tiles x 4 pairs; block 512 = 8 waves (4 mg x 2 ng), wave 32x80/64
__global__ __launch_bounds__(512, 4) void moe_gemm1(
    const float* __restrict__ x, const float* __restrict__ br, const float* __restrict__ b1,
    const unsigned char* __restrict__ B1s, unsigned char* __restrict__ ACT) {
  __shared__ __align__(16) unsigned char smem[34816];  // B [0,18432) + A [18432,34816)
  __shared__ float logit_lds[128][8];

  const int tid  = threadIdx.x;
  const int lane = tid & 63;
  const int w    = tid >> 6;
  const int mg   = w >> 1;   // rows mg*32 .. +32
  const int ng   = w & 1;    // 0: pair frags 0-3 + router ; 1: pair frags 4-7
  const int f15  = lane & 15;
  const int fhi  = lane >> 4;

  const int wid   = ((blockIdx.x & 7) << 7) + (blockIdx.x >> 3);  // XCD-chunked, 1024=8*128
  const int mtile = wid >> 2;
  const int p     = wid & 3;
  const int m0    = mtile << 7;

  f32x4 acc[2][5];
  #pragma unroll
  for (int a = 0; a < 2; ++a)
    #pragma unroll
    for (int b = 0; b < 5; ++b) acc[a][b] = f32x4{0.f, 0.f, 0.f, 0.f};

  // A staging: thread = (row tid>>2, 16-float chunk tid&3)
  const int srow = tid >> 2;
  const int scg  = tid & 3;
  const float* xrow = x + (size_t)(m0 + srow) * 1024 + scg * 16;
  unsigned char* awr0 = smem + 18432 + srow * 128 + (((scg * 2)     ^ (srow & 7)) * 16);
  unsigned char* awr1 = smem + 18432 + srow * 128 + (((scg * 2 + 1) ^ (srow & 7)) * 16);

  int bco[5];
  #pragma unroll
  for (int i = 0; i < 5; ++i) {
    int cf = ng ? (4 + i) : (i < 4 ? i : 8);
    bco[i] = (cf * 16 + f15) * 128;
  }
  const int NB = ng ? 4 : 5;

  f32x4 areg[4];
  { const f32x4* s = (const f32x4*)xrow; areg[0]=s[0]; areg[1]=s[1]; areg[2]=s[2]; areg[3]=s[3]; }

  #pragma unroll 1
  for (int ks = 0; ks < 16; ++ks) {
    __syncthreads();
    {  // stage B-tile: 18 KiB linear (swizzle pre-baked in ws)
      const unsigned char* bsrc = B1s + ks * B1S_KBSZ;
      for (int i = w; i < 18; i += 8) {
        int gc0 = (i < 16) ? (p * 128 + i * 8) : (512 + (i - 16) * 8);
        async16(bsrc + gc0 * 128 + lane * 16, smem + i * 1024 + lane * 16);
      }
    }
    {  // stage X-tile: f32 -> bf16 -> swizzled LDS
      uint4 u0, u1;
      u0.x = cvtpk(areg[0].x, areg[0].y); u0.y = cvtpk(areg[0].z, areg[0].w);
      u0.z = cvtpk(areg[1].x, areg[1].y); u0.w = cvtpk(areg[1].z, areg[1].w);
      u1.x = cvtpk(areg[2].x, areg[2].y); u1.y = cvtpk(areg[2].z, areg[2].w);
      u1.z = cvtpk(areg[3].x, areg[3].y); u1.w = cvtpk(areg[3].z, areg[3].w);
      *(uint4*)awr0 = u0; *(uint4*)awr1 = u1;
    }
    if (ks < 15) {
      const f32x4* s = (const f32x4*)(xrow + (ks + 1) * 64);
      areg[0]=s[0]; areg[1]=s[1]; areg[2]=s[2]; areg[3]=s[3];
    }
    __syncthreads();
    #pragma unroll
    for (int ksub = 0; ksub < 2; ++ksub) {
      const int ch = ((ksub * 4 + fhi) ^ (f15 & 7)) << 4;
      bf16x8 af0 = *(const bf16x8*)(smem + 18432 + (mg * 32      + f15) * 128 + ch);
      bf16x8 af1 = *(const bf16x8*)(smem + 18432 + (mg * 32 + 16 + f15) * 128 + ch);
      #pragma unroll
      for (int i = 0; i < 5; ++i) {
        if (i < NB) {
          bf16x8 bfr = *(const bf16x8*)(smem + bco[i] + ch);
          acc[0][i] = __builtin_amdgcn_mfma_f32_16x16x32_bf16(af0, bfr, acc[0][i], 0, 0, 0);
          acc[1][i] = __builtin_amdgcn_mfma_f32_16x16x32_bf16(af1, bfr, acc[1][i], 0, 0, 0);
        }
      }
    }
  }

  if (ng == 0 && f15 < 8) {  // router logits (frag idx 4 = cols 512-519), add br
    float brv = br[f15];
    #pragma unroll
    for (int mf = 0; mf < 2; ++mf)
      #pragma unroll
      for (int r = 0; r < 4; ++r)
        logit_lds[mg * 32 + mf * 16 + fhi * 4 + r][f15] = acc[mf][4][r] + brv;
  }
  __syncthreads();  // all MFMA LDS reads done; safe to alias smem as hb/pb

  const int e = p * 2 + ng;
  const float b1x0 = b1[e * 64 + f15],      b1x1 = b1[e * 64 + 16 + f15];
  const float b1g0 = b1[e * 64 + 32 + f15], b1g1 = b1[e * 64 + 48 + f15];
  unsigned short* hb = (unsigned short*)smem;              // [128][72] (144 B stride)
  unsigned short* pb = (unsigned short*)(smem + 18432);    // [128][8]

  #pragma unroll
  for (int mf = 0; mf < 2; ++mf) {
    #pragma unroll
    for (int r = 0; r < 4; ++r) {
      int row = mg * 32 + mf * 16 + fhi * 4 + r;
      float l0 = logit_lds[row][0], l1 = logit_lds[row][1];
      float l2 = logit_lds[row][2], l3 = logit_lds[row][3];
      float l4 = logit_lds[row][4], l5 = logit_lds[row][5];
      float l6 = logit_lds[row][6], l7 = logit_lds[row][7];
      float mx = fmaxf(fmaxf(fmaxf(l0, l1), fmaxf(l2, l3)),
                       fmaxf(fmaxf(l4, l5), fmaxf(l6, l7)));
      float ssum = __expf(l0 - mx) + __expf(l1 - mx) + __expf(l2 - mx) + __expf(l3 - mx) +
                   __expf(l4 - mx) + __expf(l5 - mx) + __expf(l6 - mx) + __expf(l7 - mx);
      float rinv = 1.f / ssum;
      float pe = __expf(logit_lds[row][e] - mx) * rinv;
      #pragma unroll
      for (int ci = 0; ci < 2; ++ci) {
        float xv = acc[mf][ci][r]     + (ci ? b1x1 : b1x0);
        float gv = acc[mf][ci + 2][r] + (ci ? b1g1 : b1g0);
        float av = pe * xv * gv / (1.f + __expf(-gv));  // pe * xp * silu(gate)
        hb[row * 72 + ng * 32 + ci * 16 + f15] = f2bf(av);
      }
      if (ng == 0 && f15 < 8)
        pb[row * 8 + f15] = f2bf(__expf(logit_lds[row][f15] - mx) * rinv);
    }
  }
  __syncthreads();

  {  // ACT write: this pair's 8 chunks (+ p/zero chunks from pair 0)
    const int row = tid >> 2, q = tid & 3, key = row & 7;
    unsigned char* arow = ACT + (size_t)(m0 + row) * 640;
    #pragma unroll
    for (int j = 0; j < 2; ++j) {
      int c = q * 2 + j;  // 0..7
      uint4 v = *(const uint4*)((const unsigned char*)hb + row * 144 + c * 16);
      *(uint4*)(arow + p * 128 + ((c ^ key) << 4)) = v;
    }
    if (p == 0) {  // k 256-263 = p ; k 264-319 = 0
      #pragma unroll
      for (int j = 0; j < 2; ++j) {
        int c = q * 2 + j;
        uint4 v = make_uint4(0, 0, 0, 0);
        if (c == 0) v = *(const uint4*)((const unsigned char*)pb + row * 16);
        *(uint4*)(arow + 512 + ((c ^ key) << 4)) = v;
      }
    }
  }
}

// ---------------- kernel 2: ACT @ W2s -> out ; zero-LDS, barrier-free K-loop ----------------
// grid 2048 = 256 m x 8 n; block 256 = 4 waves (2 mg x 2 ng), wave 64x64
__global__ __launch_bounds__(256, 3) void moe_gemm2(
    const unsigned char* __restrict__ ACT, const unsigned char* __restrict__ W2s,
    float* __restrict__ out) {
  __shared__ __align__(16) unsigned char smem[32768];  // epilogue slab f32[64][128]
  const int tid  = threadIdx.x;
  const int lane = tid & 63;
  const int w    = tid >> 6;
  const int mg   = w >> 1, ng = w & 1;
  const int f15  = lane & 15, fhi = lane >> 4;
  const int k7   = f15 & 7;

  const int wid = ((blockIdx.x & 7) << 8) + (blockIdx.x >> 3);  // 2048 = 8*256
  const int m0  = (wid >> 3) * 128;
  const int n0  = (wid & 7) * 128;

  f32x4 acc[4][4];
  #pragma unroll
  for (int a = 0; a < 4; ++a)
    #pragma unroll
    for (int b = 0; b < 4; ++b) acc[a][b] = f32x4{0.f, 0.f, 0.f, 0.f};

  const unsigned char* aB = ACT + (size_t)(m0 + mg * 64 + f15) * 640;
  const unsigned char* bB = W2s + (size_t)(n0 + ng * 64 + f15) * 640;
  const int ch0 = ((fhi)     ^ k7) << 4;
  const int ch1 = ((4 + fhi) ^ k7) << 4;

  #pragma unroll
  for (int kb = 0; kb < 5; ++kb) {
    bf16x8 a0[4], a1[4];
    #pragma unroll
    for (int mf = 0; mf < 4; ++mf) {
      const unsigned char* s_ = aB + mf * 10240 + kb * 128;
      a0[mf] = *(const bf16x8*)(s_ + ch0);
      a1[mf] = *(const bf16x8*)(s_ + ch1);
    }
    #pragma unroll
    for (int nf = 0; nf < 4; ++nf) {
      const unsigned char* s_ = bB + nf * 10240 + kb * 128;
      bf16x8 b0 = *(const bf16x8*)(s_ + ch0);
      bf16x8 b1v = *(const bf16x8*)(s_ + ch1);
      #pragma unroll
      for (int mf = 0; mf < 4; ++mf)
        acc[mf][nf] = __builtin_amdgcn_mfma_f32_16x16x32_bf16(a0[mf], b0, acc[mf][nf], 0, 0, 0);
      #pragma unroll
      for (int mf = 0; mf < 4; ++mf)
        acc[mf][nf] = __builtin_amdgcn_mfma_f32_16x16x32_bf16(a1[mf], b1v, acc[mf][nf], 0, 0, 0);
    }
  }

  // epilogue: two 64-row rounds through a swizzled f32 slab -> 512B coalesced stores
  float* slab = (float*)smem;
  #pragma unroll 1
  for (int q = 0; q < 2; ++q) {
    if (mg == q) {
      #pragma unroll
      for (int mf = 0; mf < 4; ++mf)
        #pragma unroll
        for (int nf = 0; nf < 4; ++nf)
          #pragma unroll
          for (int r = 0; r < 4; ++r) {
            int rl  = mf * 16 + fhi * 4 + r;
            int col = ng * 64 + nf * 16 + f15;
            slab[rl * 128 + (col ^ (((rl >> 2) & 7) << 2))] = acc[mf][nf][r];
          }
    }
    __syncthreads();
    #pragma unroll
    for (int j = 0; j < 8; ++j) {
      int rl = (tid >> 5) + j * 8;
      int c4 = tid & 31;
      f32x4 v = *(const f32x4*)(smem + rl * 512 + ((c4 ^ ((rl >> 2) & 7)) << 4));
      *(f32x4*)(out + (size_t)(m0 + q * 64 + rl) * 1024 + n0 + c4 * 4) = v;
    }
    __syncthreads();
  }
}

extern "C" void kernel_launch(void* const* d_in, const int* in_sizes, int n_in,
                              void* d_out, int out_size, void* d_ws, size_t ws_size,
                              hipStream_t stream) {
  const float* x  = (const float*)d_in[0];
  const float* Wr = (const float*)d_in[1];
  const float* br = (const float*)d_in[2];
  const float* W1 = (const float*)d_in[3];
  const float* b1 = (const float*)d_in[4];
  const float* W2 = (const float*)d_in[5];
  const float* b2 = (const float*)d_in[6];
  float* out = (float*)d_out;
  unsigned char* ws  = (unsigned char*)d_ws;
  unsigned char* B1s = ws;
  unsigned char* W2s = ws + W2S_OFF;
  unsigned char* ACT = ws + ACT_OFF;

  hipLaunchKernelGGL(prep_all, dim3(424), dim3(256), 0, stream, W1, Wr, W2, b2, B1s, W2s);
  hipLaunchKernelGGL(moe_gemm1, dim3(1024), dim3(512), 0, stream, x, br, b1, B1s, ACT);
  hipLaunchKernelGGL(moe_gemm2, dim3(2048), dim3(256), 0, stream, ACT, W2s, out);
}